// Round 4
// baseline (222.082 us; speedup 1.0000x reference)
//
#include <hip/hip_runtime.h>

#define BINS 25
#define H 512
#define W 512
#define NPLANES 96   // B*C = 32*3
#define NSH 32       // sub-histograms per block
#define BPP 4        // blocks per plane: 768 blocks = exactly 3/CU (LDS-capped)
#define RING 6       // LDS ring slots per wave (rows); 12 KB/wave

// Address-space typedefs for the global->LDS DMA builtin.
typedef const __attribute__((address_space(1))) void* gvp;
typedef __attribute__((address_space(3))) void* lvp;

// Block = 256 threads = 4 waves; block b covers plane z = b>>2, wave w owns
// strip S = 4*(b&3)+w (16 output rows, 37 input rows). Input rows are staged
// dense (CONTIGUOUS source -- the DMA fast path, >=22 B/cy/CU) into a
// per-wave 6-slot LDS ring via async global_load_lds (2 instrs/row, zero
// dest VGPRs), depth-counted with s_waitcnt vmcnt(6) -- never drained to 0
// in the loop. LDS layout is LINEAR: the stride-32B reader pattern is only
// a 2-way bank alias, which is free (m136). r3's chunk-swizzled source
// scattered the DMA return packets' LDS writes and serialized the DMA port
// (4.9M conflict cycles, 4.7 B/cy/CU) -- deleted on both sides per rule 21.
__global__ __launch_bounds__(256) void blur_hist(
        const float* __restrict__ x, const float* __restrict__ y,
        unsigned int* __restrict__ partial) {
    // XCD-contiguous swizzle (768 % 8 == 0 -> bijective): same-plane blocks
    // share an XCD L2 for halo reuse.
    const int b = ((blockIdx.x & 7) * 96) + (blockIdx.x >> 3);
    const int z = b >> 2;
    const float* src = (z < NPLANES) ? x + (size_t)z * H * W
                                     : y + (size_t)(z - NPLANES) * H * W;

    __shared__ __align__(16) float ring[4][RING][512];   // 48 KB
    __shared__ unsigned int sh[NSH * BINS];              // 3.2 KB

    const int tid = threadIdx.x;
    if (tid < (NSH * BINS / 4))
        *(float4*)((float*)sh + 4 * tid) = make_float4(0.f, 0.f, 0.f, 0.f);
    __syncthreads();

    const int l  = tid & 63;                  // x-lane
    const int wv = tid >> 6;                  // wave 0..3
    const int S  = (b & 3) * 4 + wv;          // y-strip 0..15
    const int g0 = 32 * S - 3;                // first input row of the strip

    float* const rbase = &ring[wv][0][0];

    // Stage input row index k (gy = g0+k, clamped; dummy rows keep the vmcnt
    // count uniform) into ring slot sl. 2x global_load_lds dwordx4,
    // contiguous source: lane l of instr j fetches floats 256j+4l..256j+4l+3.
    auto STAGE = [&](int k, int sl) {
        int gy = g0 + k;
        gy = min(max(gy, 0), H - 1);
        const float* rp = src + (size_t)gy * W + 4 * l;
        float* lp = rbase + sl * 512;
        __builtin_amdgcn_global_load_lds((gvp)(rp),       (lvp)lp,         16, 0, 0);
        __builtin_amdgcn_global_load_lds((gvp)(rp + 256), (lvp)(lp + 256), 16, 0, 0);
    };

    // Reader chunk positions (16B chunks), fixed across rows: chunks
    // 2l-1 .. 2l+2 = floats 8l-4 .. 8l+11 (clamped + masked at edges).
    // Per ds_read_b128: 16 lanes per bank-group = 2-way alias = free.
    const int p0 = max(2 * l - 1, 0);
    const int p1 = 2 * l;
    const int p2 = 2 * l + 1;
    const int p3 = min(2 * l + 2, 127);
    const float m0 = (l == 0)  ? 0.f : 1.f;   // left-halo zero mask
    const float m3 = (l == 63) ? 0.f : 1.f;   // right-halo zero mask

    const float w0 = 1.f/64.f, w1 = 6.f/64.f, w2 = 15.f/64.f, w3 = 20.f/64.f;

    // ds_read row k from slot sl, horizontal 7-tap blur (stride 2), zero for
    // out-of-image rows (wave-uniform rm).
    auto HROW = [&](int k, int sl) -> float4 {
        const float* rp = rbase + sl * 512;
        const float4 qa = *(const float4*)(rp + 4 * p0);
        const float4 qb = *(const float4*)(rp + 4 * p1);
        const float4 qc = *(const float4*)(rp + 4 * p2);
        const float4 qd = *(const float4*)(rp + 4 * p3);
        const int gy = g0 + k;
        const float rm = ((unsigned)gy < (unsigned)H) ? 1.f : 0.f;
        float r1 = qa.y * m0, r2 = qa.z * m0, r3 = qa.w * m0;
        float r4 = qb.x, r5 = qb.y, r6 = qb.z, r7 = qb.w;
        float r8 = qc.x, r9 = qc.y, r10 = qc.z, r11 = qc.w;
        float r12 = qd.x * m3, r13 = qd.y * m3;
        float4 h;
        h.x = (w0*(r1 + r7)  + w1*(r2 + r6)  + w2*(r3 + r5)  + w3*r4)  * rm;
        h.y = (w0*(r3 + r9)  + w1*(r4 + r8)  + w2*(r5 + r7)  + w3*r6)  * rm;
        h.z = (w0*(r5 + r11) + w1*(r6 + r10) + w2*(r7 + r9)  + w3*r8)  * rm;
        h.w = (w0*(r7 + r13) + w1*(r8 + r12) + w2*(r9 + r11) + w3*r10) * rm;
        return h;
    };

    unsigned int* wh = sh + (tid & (NSH - 1)) * BINS;
    auto binit = [&](float v) {
        int bb = min((int)(v * 25.f), BINS - 1);   // v in [0,1] by construction
        atomicAdd(&wh[bb], 1u);
    };
    auto vout = [&](const float4& h0, const float4& h1, const float4& h2,
                    const float4& h3, const float4& h4, const float4& h5,
                    const float4& h6) {
        binit(w0*(h0.x+h6.x) + w1*(h1.x+h5.x) + w2*(h2.x+h4.x) + w3*h3.x);
        binit(w0*(h0.y+h6.y) + w1*(h1.y+h5.y) + w2*(h2.y+h4.y) + w3*h3.y);
        binit(w0*(h0.z+h6.z) + w1*(h1.z+h5.z) + w2*(h2.z+h4.z) + w3*h3.z);
        binit(w0*(h0.w+h6.w) + w1*(h1.w+h5.w) + w2*(h2.w+h4.w) + w3*h3.w);
    };

    // ---- prologue: fill ring, h-blur rows 0..4 ----
    STAGE(0, 0); STAGE(1, 1); STAGE(2, 2);
    STAGE(3, 3); STAGE(4, 4); STAGE(5, 5);           // 12 DMAs in flight
    asm volatile("s_waitcnt vmcnt(2)" ::: "memory"); // rows 0..4 arrived
    float4 h0 = HROW(0, 0), h1 = HROW(1, 1), h2 = HROW(2, 2),
           h3 = HROW(3, 3), h4 = HROW(4, 4);
    asm volatile("s_waitcnt lgkmcnt(0)" ::: "memory"); // reads retired before overwrite
    STAGE(6, 0); STAGE(7, 1); STAGE(8, 2); STAGE(9, 3);

    // ---- steady state: invariant at iter j: issued <= row 2j+9, read <= 2j+4.
    // vmcnt(6) leaves the newest 3 rows in flight; never drains to 0.
    float4 h5, h6;
    #pragma unroll
    for (int j = 0; j < 16; j++) {
        const int k5 = 2 * j + 5, k6 = 2 * j + 6;
        asm volatile("s_waitcnt vmcnt(6)" ::: "memory");   // rows <= 2j+6 arrived
        h5 = HROW(k5, k5 % RING);
        h6 = HROW(k6, k6 % RING);
        asm volatile("s_waitcnt lgkmcnt(0)" ::: "memory"); // ds_reads done -> slots reusable
        STAGE(2 * j + 10, (2 * j + 10) % RING);
        STAGE(2 * j + 11, (2 * j + 11) % RING);
        vout(h0, h1, h2, h3, h4, h5, h6);
        h0 = h2; h1 = h3; h2 = h4; h3 = h5; h4 = h6;
    }
    asm volatile("s_waitcnt vmcnt(0)" ::: "memory");  // drain tail DMAs pre-exit
    __syncthreads();

    // ---- one histogram writeout per block ----
    if (tid < BINS) {
        unsigned int acc = 0;
        #pragma unroll
        for (int g = 0; g < NSH; g++) acc += sh[g * BINS + tid];
        partial[b * BINS + tid] = acc;
    }
}

// 96 blocks x 64 threads: plane p gathers its 4 block-partials for x and y,
// cosine sim, atomic mean into out[0].
__global__ __launch_bounds__(64) void reduce_cos(
        const unsigned int* __restrict__ partial, float* __restrict__ out) {
    __shared__ float sa[BINS], sb[BINS];
    const int p = blockIdx.x;
    const int t = threadIdx.x;
    if (t < BINS) {
        unsigned int a = 0, bb = 0;
        #pragma unroll
        for (int j = 0; j < BPP; j++) {
            a  += partial[((size_t)p * BPP + j) * BINS + t];
            bb += partial[((size_t)(NPLANES + p) * BPP + j) * BINS + t];
        }
        sa[t] = (float)a;
        sb[t] = (float)bb;
    }
    __syncthreads();
    if (t == 0) {
        const float inv_hw = 1.0f / (float)(H * W);
        float dot = 0.f, nx = 0.f, ny = 0.f;
        for (int k = 0; k < BINS; k++) {
            float a = sa[k] * inv_hw;
            float c = sb[k] * inv_hw;
            dot += a * c;
            nx  += a * a;
            ny  += c * c;
        }
        nx = fmaxf(sqrtf(nx), 1e-6f);
        ny = fmaxf(sqrtf(ny), 1e-6f);
        atomicAdd(out, (dot / (nx * ny)) * (1.0f / (float)NPLANES));
    }
}

extern "C" void kernel_launch(void* const* d_in, const int* in_sizes, int n_in,
                              void* d_out, int out_size, void* d_ws, size_t ws_size,
                              hipStream_t stream) {
    const float* x = (const float*)d_in[0];
    const float* y = (const float*)d_in[1];
    float* out = (float*)d_out;

    unsigned int* partial = (unsigned int*)d_ws;   // [768][25] u32 = 76.8 KB

    hipMemsetAsync(out, 0, sizeof(float), stream);

    blur_hist<<<2 * NPLANES * BPP, 256, 0, stream>>>(x, y, partial);
    reduce_cos<<<NPLANES, 64, 0, stream>>>(partial, out);
}

// Round 5
// 221.124 us; speedup vs baseline: 1.0043x; 1.0043x over previous
//
#include <hip/hip_runtime.h>

#define BINS 25
#define H 512
#define W 512
#define NPLANES 96   // B*C = 32*3
#define NSH 32       // sub-histograms per block
#define BPP 4        // blocks per plane: 768 blocks = 3/CU (LDS-capped)

// Address-space typedefs for the global->LDS DMA builtin.
typedef const __attribute__((address_space(1))) void* gvp;
typedef __attribute__((address_space(3))) void* lvp;

// m97-style block-cooperative panel pipeline. Block = 256 threads = 4 waves;
// wave w owns strip S = 4*(b&3)+w (16 output rows, input rows g0..g0+36).
// Panel p = relative rows {2p, 2p+1} of ALL FOUR strips (16 KB), staged by
// the whole block in 16 back-to-back global_load_lds (thread (w,l), k=0..3:
// strip k, parity w>>1, col-half w&1, lane l -> contiguous 1KB per instr).
// 3-slot ring: at step q, panels q+2,q+3 are read, q+4 is being staged.
// Sync is raw s_barrier + counted s_waitcnt vmcnt(4) (panel q+3 arrived;
// panel q+4 stays in flight) -- never vmcnt(0) in the loop. This replaces
// r3/r4's per-wave 2-row micro-ring whose alternating fine waits held only
// ~5 B/cy/CU delivered (80us wall at 12% VALU).
__global__ __launch_bounds__(256) void blur_hist(
        const float* __restrict__ x, const float* __restrict__ y,
        unsigned int* __restrict__ partial) {
    // XCD-contiguous swizzle (768 % 8 == 0 -> bijective).
    const int b = ((blockIdx.x & 7) * 96) + (blockIdx.x >> 3);
    const int z = b >> 2;
    const float* src = (z < NPLANES) ? x + (size_t)z * H * W
                                     : y + (size_t)(z - NPLANES) * H * W;

    __shared__ __align__(16) float ring[3][4][2][512];   // 48 KB panel ring
    __shared__ unsigned int sh[NSH * BINS];              // 3.2 KB

    const int tid = threadIdx.x;
    const int l   = tid & 63;                 // lane
    const int wv  = tid >> 6;                 // wave 0..3
    const int sb  = (b & 3) * 4;              // first strip of this block
    const int g0  = 32 * (sb + wv) - 3;       // my wave's strip origin (reads)
    const int pr  = wv >> 1;                  // staging: row parity
    const int hf  = wv & 1;                   // staging: column half

    // Stage panel p (relative rows 2p+0/1 of strips sb..sb+3) into ring[slot].
    // 4 global_load_lds per thread; LDS dest wave-uniform base + lane*16.
    auto STAGE = [&](int p, int slot) {
        #pragma unroll
        for (int k = 0; k < 4; ++k) {
            int gy = 32 * (sb + k) - 3 + 2 * p + pr;
            gy = min(max(gy, 0), H - 1);
            const float* rp = src + (size_t)gy * W + hf * 256 + 4 * l;
            __builtin_amdgcn_global_load_lds(
                (gvp)rp, (lvp)&ring[slot][k][pr][hf * 256], 16, 0, 0);
        }
    };

    if (tid < (NSH * BINS / 4))
        *(float4*)((float*)sh + 4 * tid) = make_float4(0.f, 0.f, 0.f, 0.f);

    // Reader chunk positions (16B chunks in a 512-float row): chunks
    // 2l-1..2l+2 = floats 8l-4..8l+11, clamped + masked at edges.
    const int p0 = max(2 * l - 1, 0);
    const int p1 = 2 * l;
    const int p2 = 2 * l + 1;
    const int p3 = min(2 * l + 2, 127);
    const float m0 = (l == 0)  ? 0.f : 1.f;
    const float m3 = (l == 63) ? 0.f : 1.f;
    const float w0 = 1.f/64.f, w1 = 6.f/64.f, w2 = 15.f/64.f, w3 = 20.f/64.f;

    // h-blur relative row k (0..38) of my wave's strip from the ring.
    auto HROW = [&](int k) -> float4 {
        const float* rp = &ring[(k >> 1) % 3][wv][k & 1][0];
        const float4 qa = *(const float4*)(rp + 4 * p0);
        const float4 qb = *(const float4*)(rp + 4 * p1);
        const float4 qc = *(const float4*)(rp + 4 * p2);
        const float4 qd = *(const float4*)(rp + 4 * p3);
        const int gy = g0 + k;
        const float rm = ((unsigned)gy < (unsigned)H) ? 1.f : 0.f;
        float r1 = qa.y * m0, r2 = qa.z * m0, r3 = qa.w * m0;
        float r4 = qb.x, r5 = qb.y, r6 = qb.z, r7 = qb.w;
        float r8 = qc.x, r9 = qc.y, r10 = qc.z, r11 = qc.w;
        float r12 = qd.x * m3, r13 = qd.y * m3;
        float4 h;
        h.x = (w0*(r1 + r7)  + w1*(r2 + r6)  + w2*(r3 + r5)  + w3*r4)  * rm;
        h.y = (w0*(r3 + r9)  + w1*(r4 + r8)  + w2*(r5 + r7)  + w3*r6)  * rm;
        h.z = (w0*(r5 + r11) + w1*(r6 + r10) + w2*(r7 + r9)  + w3*r8)  * rm;
        h.w = (w0*(r7 + r13) + w1*(r8 + r12) + w2*(r9 + r11) + w3*r10) * rm;
        return h;
    };

    unsigned int* wh = sh + (tid & (NSH - 1)) * BINS;
    auto binit = [&](float v) {
        int bb = min((int)(v * 25.f), BINS - 1);   // v in [0,1] by construction
        atomicAdd(&wh[bb], 1u);
    };
    auto vout = [&](const float4& h0, const float4& h1, const float4& h2,
                    const float4& h3, const float4& h4, const float4& h5,
                    const float4& h6) {
        binit(w0*(h0.x+h6.x) + w1*(h1.x+h5.x) + w2*(h2.x+h4.x) + w3*h3.x);
        binit(w0*(h0.y+h6.y) + w1*(h1.y+h5.y) + w2*(h2.y+h4.y) + w3*h3.y);
        binit(w0*(h0.z+h6.z) + w1*(h1.z+h5.z) + w2*(h2.z+h4.z) + w3*h3.z);
        binit(w0*(h0.w+h6.w) + w1*(h1.w+h5.w) + w2*(h2.w+h4.w) + w3*h3.w);
    };

    // ---- prologue: panels 0..2, window rows 0..4 ----
    STAGE(0, 0); STAGE(1, 1); STAGE(2, 2);               // 12 DMA / thread
    asm volatile("s_waitcnt vmcnt(0) lgkmcnt(0)" ::: "memory");  // once, panels 0-2 + sh zeros
    __builtin_amdgcn_s_barrier();
    asm volatile("" ::: "memory");
    float4 h0 = HROW(0), h1 = HROW(1), h2 = HROW(2),
           h3 = HROW(3), h4 = HROW(4);
    asm volatile("s_waitcnt lgkmcnt(0)" ::: "memory");   // reads retired
    __builtin_amdgcn_s_barrier();                        // before slot-0/1 reuse
    asm volatile("" ::: "memory");
    STAGE(3, 0);                                         // panel 3 -> slot 0

    // ---- steady state: 16 steps, one output row each ----
    float4 h5, h6;
    #pragma unroll
    for (int q = 0; q < 16; ++q) {
        STAGE(q + 4, (q + 4) % 3);                       // prefetch next panel
        asm volatile("s_waitcnt vmcnt(4)" ::: "memory"); // panel q+3 arrived
        __builtin_amdgcn_s_barrier();                    // A: arrival join
        asm volatile("" ::: "memory");
        h5 = HROW(2 * q + 5);                            // panel q+2, odd row
        h6 = HROW(2 * q + 6);                            // panel q+3, even row
        asm volatile("s_waitcnt lgkmcnt(0)" ::: "memory"); // reads retired
        vout(h0, h1, h2, h3, h4, h5, h6);
        h0 = h2; h1 = h3; h2 = h4; h3 = h5; h4 = h6;
        __builtin_amdgcn_s_barrier();                    // B: slot reuse safe
        asm volatile("" ::: "memory");
    }

    asm volatile("s_waitcnt vmcnt(0)" ::: "memory");     // drain tail DMAs
    __syncthreads();                                     // atomics visible

    // ---- one histogram writeout per block ----
    if (tid < BINS) {
        unsigned int acc = 0;
        #pragma unroll
        for (int g = 0; g < NSH; g++) acc += sh[g * BINS + tid];
        partial[b * BINS + tid] = acc;
    }
}

// 96 blocks x 64 threads: plane p gathers its 4 block-partials for x and y,
// cosine sim, atomic mean into out[0].
__global__ __launch_bounds__(64) void reduce_cos(
        const unsigned int* __restrict__ partial, float* __restrict__ out) {
    __shared__ float sa[BINS], sb[BINS];
    const int p = blockIdx.x;
    const int t = threadIdx.x;
    if (t < BINS) {
        unsigned int a = 0, bb = 0;
        #pragma unroll
        for (int j = 0; j < BPP; j++) {
            a  += partial[((size_t)p * BPP + j) * BINS + t];
            bb += partial[((size_t)(NPLANES + p) * BPP + j) * BINS + t];
        }
        sa[t] = (float)a;
        sb[t] = (float)bb;
    }
    __syncthreads();
    if (t == 0) {
        const float inv_hw = 1.0f / (float)(H * W);
        float dot = 0.f, nx = 0.f, ny = 0.f;
        for (int k = 0; k < BINS; k++) {
            float a = sa[k] * inv_hw;
            float c = sb[k] * inv_hw;
            dot += a * c;
            nx  += a * a;
            ny  += c * c;
        }
        nx = fmaxf(sqrtf(nx), 1e-6f);
        ny = fmaxf(sqrtf(ny), 1e-6f);
        atomicAdd(out, (dot / (nx * ny)) * (1.0f / (float)NPLANES));
    }
}

extern "C" void kernel_launch(void* const* d_in, const int* in_sizes, int n_in,
                              void* d_out, int out_size, void* d_ws, size_t ws_size,
                              hipStream_t stream) {
    const float* x = (const float*)d_in[0];
    const float* y = (const float*)d_in[1];
    float* out = (float*)d_out;

    unsigned int* partial = (unsigned int*)d_ws;   // [768][25] u32 = 76.8 KB

    hipMemsetAsync(out, 0, sizeof(float), stream);

    blur_hist<<<2 * NPLANES * BPP, 256, 0, stream>>>(x, y, partial);
    reduce_cos<<<NPLANES, 64, 0, stream>>>(partial, out);
}

// Round 6
// 219.899 us; speedup vs baseline: 1.0099x; 1.0056x over previous
//
#include <hip/hip_runtime.h>

#define BINS 25
#define H 512
#define W 512
#define NPLANES 96   // B*C = 32*3
#define NSH 32       // sub-histograms per block
#define BPP 4        // blocks per plane: 768 blocks = 3/CU at 12 waves/CU

// Pure register-batch streaming kernel. Block = 256 threads = 4 waves; block
// b covers plane z = b>>2, wave w owns strip S = 4*(b&3)+w (16 output rows,
// input rows g0..g0+36). The strip is processed in 5 fully-unrolled batches;
// each batch issues 16 INDEPENDENT global_load_dwordx4 (8 rows x 2 quads,
// 64 dest VGPRs, no overlap -- halo comes from 5 lane-shuffles per row) and
// only then consumes them: h-blur -> 7-row register window -> v-blur ->
// LDS-atomic histogram. Depth-16/wave is structural (loads+uses inside one
// unrolled batch; nothing carried across backedges except the 28-VGPR
// window), so no spills (r2) and no compiler depth-2 serialization (r0/r1).
// No LDS staging: r3/r4/r5 showed the global_load_lds DMA path caps at
// ~5 B/cy/CU on L2-cold streams regardless of ring/panel structure.
__global__ __launch_bounds__(256) void blur_hist(
        const float* __restrict__ x, const float* __restrict__ y,
        unsigned int* __restrict__ partial) {
    // XCD-contiguous swizzle (768 % 8 == 0 -> bijective).
    const int b = ((blockIdx.x & 7) * 96) + (blockIdx.x >> 3);
    const int z = b >> 2;
    const float* src = (z < NPLANES) ? x + (size_t)z * H * W
                                     : y + (size_t)(z - NPLANES) * H * W;

    __shared__ unsigned int sh[NSH * BINS];   // 3.2 KB (only LDS use)
    const int tid = threadIdx.x;
    if (tid < (NSH * BINS / 4))
        *(float4*)((float*)sh + 4 * tid) = make_float4(0.f, 0.f, 0.f, 0.f);
    __syncthreads();

    const int l  = tid & 63;                  // x-lane: owns output cols 4l..4l+3
    const int wv = tid >> 6;                  // wave 0..3
    const int S  = (b & 3) * 4 + wv;          // y-strip 0..15
    const int g0 = 32 * S - 3;                // first input row of the strip

    const float m0 = (l == 0)  ? 0.f : 1.f;   // left-halo zero mask
    const float m3 = (l == 63) ? 0.f : 1.f;   // right-halo zero mask
    const float w0 = 1.f/64.f, w1 = 6.f/64.f, w2 = 15.f/64.f, w3 = 20.f/64.f;
    const float* colp = src + 8 * l;          // lane's column base (32B aligned)

    // h-blur one raw row (q0 = floats 8l..8l+3, q1 = 8l+4..8l+7).
    // Halo via cross-lane shuffles: left lane's q1.yzw, right lane's q0.xy.
    auto HB = [&](const float4& q0, const float4& q1, int k) -> float4 {
        const float r1  = __shfl_up(q1.y, 1) * m0;   // f[8l-3]
        const float r2  = __shfl_up(q1.z, 1) * m0;   // f[8l-2]
        const float r3  = __shfl_up(q1.w, 1) * m0;   // f[8l-1]
        const float r12 = __shfl_down(q0.x, 1) * m3; // f[8l+8]
        const float r13 = __shfl_down(q0.y, 1) * m3; // f[8l+9]
        const float r4 = q0.x, r5 = q0.y, r6 = q0.z, r7 = q0.w;
        const float r8 = q1.x, r9 = q1.y, r10 = q1.z, r11 = q1.w;
        const int gy = g0 + k;
        const float rm = ((unsigned)gy < (unsigned)H) ? 1.f : 0.f;
        float4 h;
        h.x = (w0*(r1 + r7)  + w1*(r2 + r6)  + w2*(r3 + r5)  + w3*r4)  * rm;
        h.y = (w0*(r3 + r9)  + w1*(r4 + r8)  + w2*(r5 + r7)  + w3*r6)  * rm;
        h.z = (w0*(r5 + r11) + w1*(r6 + r10) + w2*(r7 + r9)  + w3*r8)  * rm;
        h.w = (w0*(r7 + r13) + w1*(r8 + r12) + w2*(r9 + r11) + w3*r10) * rm;
        return h;
    };

    unsigned int* wh = sh + (tid & (NSH - 1)) * BINS;
    auto binit = [&](float v) {
        int bb = min((int)(v * 25.f), BINS - 1);   // v in [0,1] by construction
        atomicAdd(&wh[bb], 1u);
    };
    auto vout = [&](const float4& h0, const float4& h1, const float4& h2,
                    const float4& h3, const float4& h4, const float4& h5,
                    const float4& h6) {
        binit(w0*(h0.x+h6.x) + w1*(h1.x+h5.x) + w2*(h2.x+h4.x) + w3*h3.x);
        binit(w0*(h0.y+h6.y) + w1*(h1.y+h5.y) + w2*(h2.y+h4.y) + w3*h3.y);
        binit(w0*(h0.z+h6.z) + w1*(h1.z+h5.z) + w2*(h2.z+h4.z) + w3*h3.z);
        binit(w0*(h0.w+h6.w) + w1*(h1.w+h5.w) + w2*(h2.w+h4.w) + w3*h3.w);
    };

    float4 Aq[8], Bq[8];   // batch load destinations (64 VGPR)
    float4 hw[7];          // h-blurred row window, index k%7 (folds post-unroll)

// Issue NB rows' loads back-to-back (all independent), THEN consume: h-blur
// each row into the window; at every even k>=6 emit output j=(k-6)/2.
// All indices compile-time after unroll (rule #20).
#define BATCH(RB, NB)                                                        \
    _Pragma("unroll")                                                        \
    for (int i2 = 0; i2 < (NB); ++i2) {                                      \
        int gy = g0 + (RB) + i2;                                             \
        gy = min(max(gy, 0), H - 1);                                         \
        const float* rp = colp + (size_t)gy * W;                             \
        Aq[i2] = *(const float4*)(rp);                                       \
        Bq[i2] = *(const float4*)(rp + 4);                                   \
    }                                                                        \
    _Pragma("unroll")                                                        \
    for (int i2 = 0; i2 < (NB); ++i2) {                                      \
        const int k = (RB) + i2;                                             \
        hw[k % 7] = HB(Aq[i2], Bq[i2], k);                                   \
        if (k >= 6 && (k & 1) == 0)                                          \
            vout(hw[(k - 6) % 7], hw[(k - 5) % 7], hw[(k - 4) % 7],          \
                 hw[(k - 3) % 7], hw[(k - 2) % 7], hw[(k - 1) % 7],          \
                 hw[k % 7]);                                                 \
    }

    BATCH(0, 8)    // rows 0..7   -> output j=0
    BATCH(8, 8)    // rows 8..15  -> j=1..4
    BATCH(16, 8)   // rows 16..23 -> j=5..8
    BATCH(24, 8)   // rows 24..31 -> j=9..12
    BATCH(32, 5)   // rows 32..36 -> j=13..15
#undef BATCH

    __syncthreads();

    // ---- one histogram writeout per block ----
    if (tid < BINS) {
        unsigned int acc = 0;
        #pragma unroll
        for (int g = 0; g < NSH; g++) acc += sh[g * BINS + tid];
        partial[b * BINS + tid] = acc;
    }
}

// 96 blocks x 64 threads: plane p gathers its 4 block-partials for x and y,
// cosine sim, atomic mean into out[0].
__global__ __launch_bounds__(64) void reduce_cos(
        const unsigned int* __restrict__ partial, float* __restrict__ out) {
    __shared__ float sa[BINS], sb[BINS];
    const int p = blockIdx.x;
    const int t = threadIdx.x;
    if (t < BINS) {
        unsigned int a = 0, bb = 0;
        #pragma unroll
        for (int j = 0; j < BPP; j++) {
            a  += partial[((size_t)p * BPP + j) * BINS + t];
            bb += partial[((size_t)(NPLANES + p) * BPP + j) * BINS + t];
        }
        sa[t] = (float)a;
        sb[t] = (float)bb;
    }
    __syncthreads();
    if (t == 0) {
        const float inv_hw = 1.0f / (float)(H * W);
        float dot = 0.f, nx = 0.f, ny = 0.f;
        for (int k = 0; k < BINS; k++) {
            float a = sa[k] * inv_hw;
            float c = sb[k] * inv_hw;
            dot += a * c;
            nx  += a * a;
            ny  += c * c;
        }
        nx = fmaxf(sqrtf(nx), 1e-6f);
        ny = fmaxf(sqrtf(ny), 1e-6f);
        atomicAdd(out, (dot / (nx * ny)) * (1.0f / (float)NPLANES));
    }
}

extern "C" void kernel_launch(void* const* d_in, const int* in_sizes, int n_in,
                              void* d_out, int out_size, void* d_ws, size_t ws_size,
                              hipStream_t stream) {
    const float* x = (const float*)d_in[0];
    const float* y = (const float*)d_in[1];
    float* out = (float*)d_out;

    unsigned int* partial = (unsigned int*)d_ws;   // [768][25] u32 = 76.8 KB

    hipMemsetAsync(out, 0, sizeof(float), stream);

    blur_hist<<<2 * NPLANES * BPP, 256, 0, stream>>>(x, y, partial);
    reduce_cos<<<NPLANES, 64, 0, stream>>>(partial, out);
}